// Round 17
// baseline (232.903 us; speedup 1.0000x reference)
//
#include <hip/hip_runtime.h>
#include <math.h>

typedef __bf16 bf16_t;
typedef float    f32x2 __attribute__((ext_vector_type(2)));
typedef float    f32x4 __attribute__((ext_vector_type(4)));
typedef unsigned u32x2 __attribute__((ext_vector_type(2)));
typedef unsigned u32x4 __attribute__((ext_vector_type(4)));
typedef __bf16   bf16x8 __attribute__((ext_vector_type(8)));

#define WS_MB (size_t)(1u << 20)

__device__ __forceinline__ void gl16(const bf16_t* g, bf16_t* l) {
    void* gnc = const_cast<void*>((const void*)g);
    __builtin_amdgcn_global_load_lds((__attribute__((address_space(1))) void*)gnc,
                                     (__attribute__((address_space(3))) void*)l,
                                     16, 0, 0);
}

__device__ __forceinline__ float dot4(f32x4 a, f32x4 b) {
    return a.x * b.x + a.y * b.y + a.z * b.z + a.w * b.w;
}

// bijective XCD swizzle [m204]: consecutive LOGICAL ids land on the same XCD.
__device__ __forceinline__ int xcd_swz(int orig, int nwg) {
    int q = nwg >> 3, r = nwg & 7;
    int x = orig & 7, i = orig >> 3;
    int base = (x < r) ? x * (q + 1) : r * (q + 1) + (x - r) * q;
    return base + i;
}

// ---------------- fused f32 -> bf16 convert for all 6 weight tensors (+cnt zero) -------
__global__ __launch_bounds__(256) void cvt_all_kernel(
    const float* __restrict__ s0, const float* __restrict__ s1,
    const float* __restrict__ s2, const float* __restrict__ s3,
    const float* __restrict__ s4, const float* __restrict__ s5,
    bf16_t* __restrict__ d0, bf16_t* __restrict__ d1,
    bf16_t* __restrict__ d2, bf16_t* __restrict__ d3,
    bf16_t* __restrict__ d4, bf16_t* __restrict__ d5,
    int* __restrict__ cnt) {
    if (blockIdx.x == 0 && threadIdx.x < 4) cnt[threadIdx.x] = 0;
    int i = blockIdx.x * 256 + threadIdx.x;
    const float* s; bf16_t* d; int off;
    if (i < 262144) {
        int seg = i >> 16; off = i & 65535;
        s = seg == 0 ? s0 : seg == 1 ? s1 : seg == 2 ? s2 : s3;
        d = seg == 0 ? d0 : seg == 1 ? d1 : seg == 2 ? d2 : d3;
    } else if (i < 1310720) { s = s4; d = d4; off = i - 262144; }
    else                    { s = s5; d = d5; off = i - 1310720; }
    f32x4 v = ((const f32x4*)s)[off];
    union { bf16_t b[4]; u32x2 u; } p;
    p.b[0] = (bf16_t)v.x; p.b[1] = (bf16_t)v.y;
    p.b[2] = (bf16_t)v.z; p.b[3] = (bf16_t)v.w;
    ((u32x2*)d)[off] = p.u;
}

// ---------------- RMSNorm (ln1): f32 in -> bf16 out ----------------
__global__ __launch_bounds__(256) void rmsnorm_kernel(const float* __restrict__ x,
                                                      const float* __restrict__ w,
                                                      bf16_t* __restrict__ out) {
    int row = blockIdx.x;
    const float* xr = x + (size_t)row * 512;
    int t = threadIdx.x;
    f32x2 v = *(const f32x2*)(xr + t * 2);
    float ss = v.x * v.x + v.y * v.y;
#pragma unroll
    for (int o = 32; o > 0; o >>= 1) ss += __shfl_down(ss, o);
    __shared__ float red[4];
    if ((t & 63) == 0) red[t >> 6] = ss;
    __syncthreads();
    float tot = (red[0] + red[1]) + (red[2] + red[3]);
    float sc = rsqrtf(tot * (1.0f / 512.0f) + 1e-5f);
    f32x2 wv = *(const f32x2*)(w + t * 2);
    union { bf16_t b[2]; unsigned u; } p;
    p.b[0] = (bf16_t)(v.x * sc * wv.x);
    p.b[1] = (bf16_t)(v.y * sc * wv.y);
    *(unsigned*)(out + (size_t)row * 512 + t * 2) = p.u;
}

// fast GELU (tanh-form via v_exp_f32): |err| <= ~3e-4 vs erf-GELU, << bf16 rounding.
__device__ inline float gelu_fast(float x) {
    float u = -1.5957691216f * x * fmaf(0.044715f * x, x, 1.0f);
    return x / (1.0f + __expf(u));
}

// ---------------- dense bf16 MFMA GEMM: 128x64 tiles + XCD + LDS swizzle ----------------
// Wave = 64x32 quadrant, acc[4][2]. Single-buffer 2-phase (R12 structure).
// EPI: 1 = f32 out = acc + aux[idx]; 4 = bf16 out = acc. ncol in 64-col units.
template <int EPI>
__global__ __launch_bounds__(256) void gemm_kernel(const bf16_t* __restrict__ A,
                                                   const bf16_t* __restrict__ B,
                                                   void* __restrict__ C,
                                                   const float* __restrict__ aux,
                                                   int N, int K, int ncol) {
    const int id = xcd_swz(blockIdx.x, gridDim.x);
    const int row0 = (id / ncol) * 128;
    const int col0 = (id % ncol) * 64;
    __shared__ __align__(16) bf16_t lds_a[128 * 64];   // 16 KB
    __shared__ __align__(16) bf16_t lds_b[64 * 64];    //  8 KB
    const int t = threadIdx.x;
    const bf16_t* Ap = A + (size_t)row0 * K;
    const bf16_t* Bp = B + (size_t)col0 * K;
    const int lane = t & 63, wave = t >> 6;
    const int wr = (wave >> 1) * 64, wc = (wave & 1) * 32;
    const int lrow = lane & 15;
    const int sg = lane >> 4, lr3 = lane & 7;
    const int srow = lane >> 3;
    const int scolx = ((lane & 7) ^ (lane >> 3)) * 8;

    f32x4 acc[4][2];
    f32x4 zero = {0.f, 0.f, 0.f, 0.f};
#pragma unroll
    for (int i = 0; i < 4; i++)
#pragma unroll
        for (int j = 0; j < 2; j++) acc[i][j] = zero;

    for (int k0 = 0; k0 < K; k0 += 64) {
        __syncthreads();
#pragma unroll
        for (int c = 0; c < 4; ++c) {
            const int rbase = wave * 32 + c * 8;
            gl16(Ap + (size_t)(rbase + srow) * K + k0 + scolx, lds_a + rbase * 64);
        }
        {
            const int rbase = wave * 16;
            gl16(Bp + (size_t)(rbase + srow) * K + k0 + scolx, lds_b + rbase * 64);
            gl16(Bp + (size_t)(rbase + 8 + srow) * K + k0 + scolx, lds_b + (rbase + 8) * 64);
        }
        __syncthreads();
#pragma unroll
        for (int kk = 0; kk < 2; ++kk) {
            bf16x8 af[4], bfr[2];
#pragma unroll
            for (int mi = 0; mi < 4; mi++)
                af[mi] = *(const bf16x8*)(lds_a + (wr + mi * 16 + lrow) * 64
                                          + (((kk * 4 + sg) ^ lr3) * 8));
#pragma unroll
            for (int ni = 0; ni < 2; ni++)
                bfr[ni] = *(const bf16x8*)(lds_b + (wc + ni * 16 + lrow) * 64
                                           + (((kk * 4 + sg) ^ lr3) * 8));
#pragma unroll
            for (int mi = 0; mi < 4; mi++) {
#pragma unroll
                for (int ni = 0; ni < 2; ni++) {
                    acc[mi][ni] = __builtin_amdgcn_mfma_f32_16x16x32_bf16(
                        af[mi], bfr[ni], acc[mi][ni], 0, 0, 0);
                }
            }
        }
    }

#pragma unroll
    for (int mi = 0; mi < 4; mi++) {
        int rbase = row0 + wr + mi * 16 + (lane >> 4) * 4;
#pragma unroll
        for (int ni = 0; ni < 2; ni++) {
            int col = col0 + wc + ni * 16 + (lane & 15);
#pragma unroll
            for (int r = 0; r < 4; r++) {
                float v = acc[mi][ni][r];
                size_t idx = (size_t)(rbase + r) * N + col;
                if (EPI == 1) ((float*)C)[idx] = v + aux[idx];
                else          ((bf16_t*)C)[idx] = (bf16_t)v;
            }
        }
    }
}

// ---------------- fused MoE fc: 64x64 tiles (pj-proven geometry), grid 8384 ----------
__global__ __launch_bounds__(256) void moe_fc_kernel(
    const bf16_t* __restrict__ A, const bf16_t* __restrict__ B, bf16_t* __restrict__ H,
    const int* __restrict__ list, const int* __restrict__ cnt, const int* __restrict__ seg) {
    const int id = xcd_swz(blockIdx.x, gridDim.x);
    const int row0g = (id >> 5) * 64;         // ncol = 32; seg 128-aligned -> no straddle
    const int col0 = (id & 31) * 64;
    int e = 0;
    if (row0g >= seg[1]) e = 1;
    if (row0g >= seg[2]) e = 2;
    if (row0g >= seg[3]) e = 3;
    const int ce = cnt[e];
    const int rl0 = row0g - seg[e];
    if (rl0 >= ce) return;   // gap: uniform exit before any barrier

    __shared__ __align__(16) bf16_t lds_a[64 * 64];    // 8 KB
    __shared__ __align__(16) bf16_t lds_b[64 * 64];    // 8 KB
    const int t = threadIdx.x;
    const bf16_t* Bp = B + ((size_t)e * 2048 + col0) * 512;
    const int* le = list + e * 8192;
    const int lane = t & 63, wave = t >> 6;
    const int wr = (wave >> 1) * 32, wc = (wave & 1) * 32;
    const int lrow = lane & 15;
    const int sg = lane >> 4, lr3 = lane & 7;
    const int srow = lane >> 3;
    const int scolx = ((lane & 7) ^ (lane >> 3)) * 8;

    const bf16_t* Asrc[2];
#pragma unroll
    for (int c = 0; c < 2; ++c) {
        int r = rl0 + wave * 16 + c * 8 + srow;
        r = (r < ce) ? r : (ce - 1);
        Asrc[c] = A + (size_t)le[r] * 512 + scolx;
    }

    f32x4 acc[2][2];
    f32x4 zero = {0.f, 0.f, 0.f, 0.f};
#pragma unroll
    for (int i = 0; i < 2; i++)
#pragma unroll
        for (int j = 0; j < 2; j++) acc[i][j] = zero;

    for (int k0 = 0; k0 < 512; k0 += 64) {
        __syncthreads();
#pragma unroll
        for (int c = 0; c < 2; ++c) {
            const int rbase = wave * 16 + c * 8;
            gl16(Asrc[c] + k0, lds_a + rbase * 64);
            gl16(Bp + (size_t)(rbase + srow) * 512 + k0 + scolx, lds_b + rbase * 64);
        }
        __syncthreads();
#pragma unroll
        for (int kk = 0; kk < 2; ++kk) {
            bf16x8 af[2], bfr[2];
#pragma unroll
            for (int mi = 0; mi < 2; mi++)
                af[mi] = *(const bf16x8*)(lds_a + (wr + mi * 16 + lrow) * 64
                                          + (((kk * 4 + sg) ^ lr3) * 8));
#pragma unroll
            for (int ni = 0; ni < 2; ni++)
                bfr[ni] = *(const bf16x8*)(lds_b + (wc + ni * 16 + lrow) * 64
                                           + (((kk * 4 + sg) ^ lr3) * 8));
#pragma unroll
            for (int mi = 0; mi < 2; mi++) {
#pragma unroll
                for (int ni = 0; ni < 2; ni++) {
                    acc[mi][ni] = __builtin_amdgcn_mfma_f32_16x16x32_bf16(
                        af[mi], bfr[ni], acc[mi][ni], 0, 0, 0);
                }
            }
        }
    }

#pragma unroll
    for (int mi = 0; mi < 2; mi++) {
        int rbase = row0g + wr + mi * 16 + (lane >> 4) * 4;
#pragma unroll
        for (int ni = 0; ni < 2; ni++) {
            int col = col0 + wc + ni * 16 + (lane & 15);
#pragma unroll
            for (int r = 0; r < 4; r++) {
                // rows beyond cnt within block are dup garbage; proj discards them
                H[(size_t)(rbase + r) * 2048 + col] = (bf16_t)gelu_fast(acc[mi][ni][r]);
            }
        }
    }
}

// ---------------- fused MoE proj: 64x64 tiles (R15-proven), grid 2096 ----------------
__global__ __launch_bounds__(256) void moe_pj_kernel(
    const bf16_t* __restrict__ H, const bf16_t* __restrict__ B, float* __restrict__ xout,
    const float* __restrict__ rw, const int* __restrict__ list,
    const int* __restrict__ cnt, const int* __restrict__ seg) {
    const int id = xcd_swz(blockIdx.x, gridDim.x);
    const int row0g = (id >> 3) * 64;
    const int col0 = (id & 7) * 64;
    int e = 0;
    if (row0g >= seg[1]) e = 1;
    if (row0g >= seg[2]) e = 2;
    if (row0g >= seg[3]) e = 3;
    const int ce = cnt[e];
    const int se = seg[e];
    const int rl0 = row0g - se;
    if (rl0 >= ce) return;

    __shared__ __align__(16) bf16_t lds_a[64 * 64];    // 8 KB
    __shared__ __align__(16) bf16_t lds_b[64 * 64];    // 8 KB
    const int t = threadIdx.x;
    const bf16_t* Ap = H + (size_t)row0g * 2048;
    const bf16_t* Bp = B + ((size_t)e * 512 + col0) * 2048;
    const int* le = list + e * 8192;
    const int lane = t & 63, wave = t >> 6;
    const int wr = (wave >> 1) * 32, wc = (wave & 1) * 32;
    const int lrow = lane & 15;
    const int sg = lane >> 4, lr3 = lane & 7;
    const int srow = lane >> 3;
    const int scolx = ((lane & 7) ^ (lane >> 3)) * 8;

    f32x4 acc[2][2];
    f32x4 zero = {0.f, 0.f, 0.f, 0.f};
#pragma unroll
    for (int i = 0; i < 2; i++)
#pragma unroll
        for (int j = 0; j < 2; j++) acc[i][j] = zero;

    for (int k0 = 0; k0 < 2048; k0 += 64) {
        __syncthreads();
#pragma unroll
        for (int c = 0; c < 2; ++c) {
            const int rbase = wave * 16 + c * 8;
            gl16(Ap + (size_t)(rbase + srow) * 2048 + k0 + scolx, lds_a + rbase * 64);
            gl16(Bp + (size_t)(rbase + srow) * 2048 + k0 + scolx, lds_b + rbase * 64);
        }
        __syncthreads();
#pragma unroll
        for (int kk = 0; kk < 2; ++kk) {
            bf16x8 af[2], bfr[2];
#pragma unroll
            for (int mi = 0; mi < 2; mi++)
                af[mi] = *(const bf16x8*)(lds_a + (wr + mi * 16 + lrow) * 64
                                          + (((kk * 4 + sg) ^ lr3) * 8));
#pragma unroll
            for (int ni = 0; ni < 2; ni++)
                bfr[ni] = *(const bf16x8*)(lds_b + (wc + ni * 16 + lrow) * 64
                                           + (((kk * 4 + sg) ^ lr3) * 8));
#pragma unroll
            for (int mi = 0; mi < 2; mi++) {
#pragma unroll
                for (int ni = 0; ni < 2; ni++) {
                    acc[mi][ni] = __builtin_amdgcn_mfma_f32_16x16x32_bf16(
                        af[mi], bfr[ni], acc[mi][ni], 0, 0, 0);
                }
            }
        }
    }

#pragma unroll
    for (int mi = 0; mi < 2; mi++) {
        int rbase = row0g + wr + mi * 16 + (lane >> 4) * 4;
#pragma unroll
        for (int ni = 0; ni < 2; ni++) {
            int col = col0 + wc + ni * 16 + (lane & 15);
#pragma unroll
            for (int r = 0; r < 4; r++) {
                int rloc = rbase + r - se;
                if (rloc < ce) {
                    int tok = le[rloc];
                    atomicAdd(xout + (size_t)tok * 512 + col,
                              rw[(size_t)tok * 4 + e] * acc[mi][ni][r]);
                }
            }
        }
    }
}

// ---------------- MFMA causal flash attention (packed QKV, load-ahead pipelined) -------
__global__ __launch_bounds__(256) void attn_kernel(const bf16_t* __restrict__ QKV,
                                                   bf16_t* __restrict__ O) {
    __shared__ __align__(16) bf16_t klds[2 * 64 * 32];
    __shared__ __align__(16) bf16_t vlds[4 * 2 * 16 * 32];

    const int bx = blockIdx.x;
    const int qb = 15 - (bx >> 6);
    const int bh = bx & 63;
    const int b = bh >> 3, h = bh & 7;
    const int t = threadIdx.x;
    const int lane = t & 63, wave = t >> 6;
    const int g = lane >> 4, q15 = lane & 15;
    const int qbase = qb * 64 + wave * 16;
    const int qabs = qbase + q15;

    const bf16_t* Qb = QKV + (size_t)b * 1024 * 1536 + h * 64;
    const bf16_t* Kb = Qb + 512;
    const bf16_t* Vb = Qb + 1024;

    const bf16_t* qp = Qb + (size_t)qabs * 1536 + g * 8;
    bf16x8 qf0 = *(const bf16x8*)(qp);
    bf16x8 qf1 = *(const bf16x8*)(qp + 32);

    f32x4 acc[4];
    f32x4 zero = {0.f, 0.f, 0.f, 0.f};
#pragma unroll
    for (int i = 0; i < 4; i++) acc[i] = zero;
    float m = -1e30f, denom = 0.f;

    const int kr1 = t >> 3, kc1 = t & 7;
    const int vr = t & 63, vc1 = t >> 6, vc2 = vc1 + 4;
    const int perm = ((q15 >> 2) * 8) + (q15 & 3);

    const int nkt = qb + 1;
    u32x4 ka  = *(const u32x4*)(Kb + (size_t)(kr1) * 1536 + kc1 * 8);
    u32x4 kb2 = *(const u32x4*)(Kb + (size_t)(kr1 + 32) * 1536 + kc1 * 8);
    u32x4 va  = *(const u32x4*)(Vb + (size_t)(vr) * 1536 + vc1 * 8);
    u32x4 vb2 = *(const u32x4*)(Vb + (size_t)(vr) * 1536 + vc2 * 8);

    for (int kt = 0; kt < nkt; ++kt) {
        __syncthreads();
        *(u32x4*)(klds + (kc1 >> 2) * 2048 + kr1 * 32 + (kc1 & 3) * 8) = ka;
        *(u32x4*)(klds + (kc1 >> 2) * 2048 + (kr1 + 32) * 32 + (kc1 & 3) * 8) = kb2;
        {
            union { u32x4 u; bf16_t e[8]; } tv;
            const int kh = vr >> 5, k32 = vr & 31;
            tv.u = va;
#pragma unroll
            for (int j = 0; j < 8; ++j) {
                int d = vc1 * 8 + j;
                vlds[(((d >> 4) * 2 + kh) * 16 + (d & 15)) * 32 + k32] = tv.e[j];
            }
            tv.u = vb2;
#pragma unroll
            for (int j = 0; j < 8; ++j) {
                int d = vc2 * 8 + j;
                vlds[(((d >> 4) * 2 + kh) * 16 + (d & 15)) * 32 + k32] = tv.e[j];
            }
        }
        __syncthreads();

        if (kt + 1 < nkt) {
            const size_t krow = (size_t)((kt + 1) * 64);
            ka  = *(const u32x4*)(Kb + (krow + kr1) * 1536 + kc1 * 8);
            kb2 = *(const u32x4*)(Kb + (krow + kr1 + 32) * 1536 + kc1 * 8);
            va  = *(const u32x4*)(Vb + (krow + vr) * 1536 + vc1 * 8);
            vb2 = *(const u32x4*)(Vb + (krow + vr) * 1536 + vc2 * 8);
        }

        for (int s32 = 0; s32 < 2; ++s32) {
            const int KB = kt * 64 + s32 * 32;
            if (KB > qbase + 15) break;
            const int r0 = s32 * 32 + perm;
            bf16x8 k00 = *(const bf16x8*)(klds + r0 * 32 + g * 8);
            bf16x8 k01 = *(const bf16x8*)(klds + 2048 + r0 * 32 + g * 8);
            bf16x8 k10 = *(const bf16x8*)(klds + (r0 + 4) * 32 + g * 8);
            bf16x8 k11 = *(const bf16x8*)(klds + 2048 + (r0 + 4) * 32 + g * 8);
            f32x4 s0 = zero, s1 = zero;
            s0 = __builtin_amdgcn_mfma_f32_16x16x32_bf16(k00, qf0, s0, 0, 0, 0);
            s0 = __builtin_amdgcn_mfma_f32_16x16x32_bf16(k01, qf1, s0, 0, 0, 0);
            s1 = __builtin_amdgcn_mfma_f32_16x16x32_bf16(k10, qf0, s1, 0, 0, 0);
            s1 = __builtin_amdgcn_mfma_f32_16x16x32_bf16(k11, qf1, s1, 0, 0, 0);

            const int kbg = KB + 8 * g;
            float sv[8];
#pragma unroll
            for (int r = 0; r < 4; ++r) {
                sv[r]     = (kbg + r     <= qabs) ? s0[r] * 0.125f : -1e30f;
                sv[4 + r] = (kbg + 4 + r <= qabs) ? s1[r] * 0.125f : -1e30f;
            }
            float tm = sv[0];
#pragma unroll
            for (int j = 1; j < 8; ++j) tm = fmaxf(tm, sv[j]);
            tm = fmaxf(tm, __shfl_xor(tm, 16));
            tm = fmaxf(tm, __shfl_xor(tm, 32));
            const float mn = fmaxf(m, tm);
            const float co = __expf(m - mn);
            float p[8];
            float ts = 0.f;
#pragma unroll
            for (int j = 0; j < 8; ++j) { p[j] = __expf(sv[j] - mn); ts += p[j]; }
            ts += __shfl_xor(ts, 16);
            ts += __shfl_xor(ts, 32);
            denom = denom * co + ts;
            m = mn;
            union { bf16_t e[8]; bf16x8 v; } pp;
#pragma unroll
            for (int j = 0; j < 8; ++j) pp.e[j] = (bf16_t)p[j];

#pragma unroll
            for (int db = 0; db < 4; ++db) {
                acc[db] *= co;
                bf16x8 vf = *(const bf16x8*)(vlds + ((db * 2 + s32) * 16 + q15) * 32 + g * 8);
                acc[db] = __builtin_amdgcn_mfma_f32_16x16x32_bf16(vf, pp.v, acc[db], 0, 0, 0);
            }
        }
    }

    const float inv = 1.0f / denom;
    bf16_t* op = O + (size_t)b * 1024 * 512 + h * 64 + (size_t)qabs * 512;
#pragma unroll
    for (int db = 0; db < 4; ++db) {
        union { bf16_t e[4]; u32x2 u; } w;
#pragma unroll
        for (int r = 0; r < 4; ++r) w.e[r] = (bf16_t)(acc[db][r] * inv);
        *(u32x2*)(op + db * 16 + g * 4) = w.u;
    }
}

// 128-aligned exclusive prefix of cnt -> seg (padded compact H segments)
__global__ void seg_kernel(const int* __restrict__ cnt, int* __restrict__ seg) {
    if (threadIdx.x == 0) {
        int b = 0;
#pragma unroll
        for (int e = 0; e < 4; ++e) { seg[e] = b; b += (cnt[e] + 127) & ~127; }
    }
}

// ---------------- router: fused rmsnorm2 + gate + top2 + compaction ----------------
__global__ __launch_bounds__(256) void router_kernel(
    const float* __restrict__ xr, const float* __restrict__ w,
    const float* __restrict__ gw, bf16_t* __restrict__ hb,
    float* __restrict__ rout, int* __restrict__ list, int* __restrict__ cnt) {
    __shared__ int lcnt[4], gb[4];
    __shared__ int ent_tok[64], ent_e[64], ent_r[64];
    const int t = threadIdx.x, lane = t & 63, wave = t >> 6;
    if (t < 4) lcnt[t] = 0;
    __syncthreads();

    const f32x4 w0  = *(const f32x4*)(w + lane * 8);
    const f32x4 w1  = *(const f32x4*)(w + lane * 8 + 4);
    const f32x4 g00 = *(const f32x4*)(gw + lane * 8);
    const f32x4 g01 = *(const f32x4*)(gw + lane * 8 + 4);
    const f32x4 g10 = *(const f32x4*)(gw + 512 + lane * 8);
    const f32x4 g11 = *(const f32x4*)(gw + 512 + lane * 8 + 4);
    const f32x4 g20 = *(const f32x4*)(gw + 1024 + lane * 8);
    const f32x4 g21 = *(const f32x4*)(gw + 1024 + lane * 8 + 4);
    const f32x4 g30 = *(const f32x4*)(gw + 1536 + lane * 8);
    const f32x4 g31 = *(const f32x4*)(gw + 1536 + lane * 8 + 4);

    for (int it = 0; it < 8; ++it) {
        const int tok = blockIdx.x * 32 + wave * 8 + it;
        const float* row = xr + (size_t)tok * 512 + lane * 8;
        f32x4 v0 = *(const f32x4*)(row);
        f32x4 v1 = *(const f32x4*)(row + 4);
        float ss = dot4(v0, v0) + dot4(v1, v1);
        f32x4 xw0, xw1;
        xw0.x = v0.x * w0.x; xw0.y = v0.y * w0.y; xw0.z = v0.z * w0.z; xw0.w = v0.w * w0.w;
        xw1.x = v1.x * w1.x; xw1.y = v1.y * w1.y; xw1.z = v1.z * w1.z; xw1.w = v1.w * w1.w;
        float d0 = dot4(xw0, g00) + dot4(xw1, g01);
        float d1 = dot4(xw0, g10) + dot4(xw1, g11);
        float d2 = dot4(xw0, g20) + dot4(xw1, g21);
        float d3 = dot4(xw0, g30) + dot4(xw1, g31);
#pragma unroll
        for (int o = 32; o > 0; o >>= 1) {
            ss += __shfl_xor(ss, o);
            d0 += __shfl_xor(d0, o);
            d1 += __shfl_xor(d1, o);
            d2 += __shfl_xor(d2, o);
            d3 += __shfl_xor(d3, o);
        }
        const float sc = rsqrtf(ss * (1.0f / 512.0f) + 1e-5f);
        union { bf16_t b[8]; u32x4 u; } hw;
        hw.b[0] = (bf16_t)(xw0.x * sc); hw.b[1] = (bf16_t)(xw0.y * sc);
        hw.b[2] = (bf16_t)(xw0.z * sc); hw.b[3] = (bf16_t)(xw0.w * sc);
        hw.b[4] = (bf16_t)(xw1.x * sc); hw.b[5] = (bf16_t)(xw1.y * sc);
        hw.b[6] = (bf16_t)(xw1.z * sc); hw.b[7] = (bf16_t)(xw1.w * sc);
        *(u32x4*)(hb + (size_t)tok * 512 + lane * 8) = hw.u;

        const float l0 = d0 * sc, l1 = d1 * sc, l2 = d2 * sc, l3 = d3 * sc;
        float mx = fmaxf(fmaxf(l0, l1), fmaxf(l2, l3));
        float p[4];
        p[0] = expf(l0 - mx); p[1] = expf(l1 - mx);
        p[2] = expf(l2 - mx); p[3] = expf(l3 - mx);
        float s = (p[0] + p[1]) + (p[2] + p[3]);
        float is = 1.0f / s;
        p[0] *= is; p[1] *= is; p[2] *= is; p[3] *= is;
        int i0 = 0; float b0 = p[0];
#pragma unroll
        for (int e = 1; e < 4; e++) if (p[e] > b0) { b0 = p[e]; i0 = e; }
        int i1 = -1; float b1 = -1.f;
#pragma unroll
        for (int e = 0; e < 4; e++) {
            if (e == i0) continue;
            if (p[e] > b1) { b1 = p[e]; i1 = e; }
        }
        if (lane == 0) {
            float inv2 = 1.0f / fmaxf(b0 + b1, 1e-6f);
            float o[4] = {0.f, 0.f, 0.f, 0.f};
            o[i0] = b0 * inv2;
            o[i1] = b1 * inv2;
            f32x4 ov; ov.x = o[0]; ov.y = o[1]; ov.z = o[2]; ov.w = o[3];
            *(f32x4*)(rout + (size_t)tok * 4) = ov;
            int r0 = atomicAdd(&lcnt[i0], 1);
            int r1 = atomicAdd(&lcnt[i1], 1);
            int ei = (wave * 8 + it) * 2;
            ent_tok[ei] = tok;     ent_e[ei] = i0;     ent_r[ei] = r0;
            ent_tok[ei + 1] = tok; ent_e[ei + 1] = i1; ent_r[ei + 1] = r1;
        }
    }
    __syncthreads();
    if (t < 4) gb[t] = atomicAdd(&cnt[t], lcnt[t]);
    __syncthreads();
    if (t < 64) {
        int e = ent_e[t];
        list[e * 8192 + gb[e] + ent_r[t]] = ent_tok[t];
    }
}

extern "C" void kernel_launch(void* const* d_in, const int* in_sizes, int n_in,
                              void* d_out, int out_size, void* d_ws, size_t ws_size,
                              hipStream_t stream) {
    (void)in_sizes; (void)n_in; (void)out_size; (void)ws_size;
    const float* x   = (const float*)d_in[0];
    const float* ln1 = (const float*)d_in[1];
    const float* ln2 = (const float*)d_in[2];
    const float* wq  = (const float*)d_in[3];
    const float* wk  = (const float*)d_in[4];
    const float* wv  = (const float*)d_in[5];
    const float* wo  = (const float*)d_in[6];
    const float* gw  = (const float*)d_in[7];
    const float* wfc = (const float*)d_in[8];
    const float* wpj = (const float*)d_in[9];

    char* ws = (char*)d_ws;
    bf16_t* hb    = (bf16_t*)(ws);
    bf16_t* qkvb  = (bf16_t*)(ws + 8 * WS_MB);
    bf16_t* attb  = (bf16_t*)(ws + 32 * WS_MB);
    bf16_t* Hb    = (bf16_t*)(ws + 8 * WS_MB);   // padded compact H, overlaps qkv/att
    bf16_t* wqkvb = (bf16_t*)(ws + 74 * WS_MB);
    bf16_t* wob   = (bf16_t*)(ws + 74 * WS_MB + 1536 * 1024);
    bf16_t* wfcb  = (bf16_t*)(ws + 76 * WS_MB);
    bf16_t* wpjb  = (bf16_t*)(ws + 84 * WS_MB);
    int*    list  = (int*)(ws + 92 * WS_MB);      // [4][8192]
    int*    cnt   = (int*)(ws + 92 * WS_MB + 192 * 1024);
    int*    seg   = cnt + 8;

    float* xout   = (float*)d_out;
    float* router = xout + (size_t)8192 * 512;

    cvt_all_kernel<<<9216, 256, 0, stream>>>(wq, wk, wv, wo, wfc, wpj,
                                             wqkvb, wqkvb + 512 * 512, wqkvb + 1024 * 512,
                                             wob, wfcb, wpjb, cnt);

    rmsnorm_kernel<<<8192, 256, 0, stream>>>(x, ln1, hb);
    gemm_kernel<4><<<1536, 256, 0, stream>>>(hb, wqkvb, (void*)qkvb, nullptr, 1536, 512, 24);

    attn_kernel<<<1024, 256, 0, stream>>>(qkvb, attb);

    gemm_kernel<1><<<512, 256, 0, stream>>>(attb, wob, (void*)xout, x, 512, 512, 8);

    router_kernel<<<256, 256, 0, stream>>>(xout, ln2, gw, hb, router, list, cnt);
    seg_kernel<<<1, 64, 0, stream>>>(cnt, seg);

    // fused MoE: fc 64x64 tiles (8384 blocks) + pj 64x64 tiles (2096 blocks)
    moe_fc_kernel<<<32 * 262, 256, 0, stream>>>(hb, wfcb, Hb, list, cnt, seg);
    moe_pj_kernel<<<8 * 262, 256, 0, stream>>>(Hb, wpjb, xout, router, list, cnt, seg);
}

// Round 18
// 226.505 us; speedup vs baseline: 1.0282x; 1.0282x over previous
//
#include <hip/hip_runtime.h>
#include <math.h>

typedef __bf16 bf16_t;
typedef float    f32x2 __attribute__((ext_vector_type(2)));
typedef float    f32x4 __attribute__((ext_vector_type(4)));
typedef unsigned u32x2 __attribute__((ext_vector_type(2)));
typedef unsigned u32x4 __attribute__((ext_vector_type(4)));
typedef __bf16   bf16x8 __attribute__((ext_vector_type(8)));

#define WS_MB (size_t)(1u << 20)

__device__ __forceinline__ void gl16(const bf16_t* g, bf16_t* l) {
    void* gnc = const_cast<void*>((const void*)g);
    __builtin_amdgcn_global_load_lds((__attribute__((address_space(1))) void*)gnc,
                                     (__attribute__((address_space(3))) void*)l,
                                     16, 0, 0);
}

__device__ __forceinline__ float dot4(f32x4 a, f32x4 b) {
    return a.x * b.x + a.y * b.y + a.z * b.z + a.w * b.w;
}

// bijective XCD swizzle [m204]: consecutive LOGICAL ids land on the same XCD.
__device__ __forceinline__ int xcd_swz(int orig, int nwg) {
    int q = nwg >> 3, r = nwg & 7;
    int x = orig & 7, i = orig >> 3;
    int base = (x < r) ? x * (q + 1) : r * (q + 1) + (x - r) * q;
    return base + i;
}

// ---------------- fused f32 -> bf16 convert, 8 f32/thread (+cnt zero) ----------------
// 32B/thread load granularity; grid 4608 (1179648 8-elem units).
__global__ __launch_bounds__(256) void cvt_all_kernel(
    const float* __restrict__ s0, const float* __restrict__ s1,
    const float* __restrict__ s2, const float* __restrict__ s3,
    const float* __restrict__ s4, const float* __restrict__ s5,
    bf16_t* __restrict__ d0, bf16_t* __restrict__ d1,
    bf16_t* __restrict__ d2, bf16_t* __restrict__ d3,
    bf16_t* __restrict__ d4, bf16_t* __restrict__ d5,
    int* __restrict__ cnt) {
    if (blockIdx.x == 0 && threadIdx.x < 4) cnt[threadIdx.x] = 0;
    int i = blockIdx.x * 256 + threadIdx.x;   // 8-elem unit index
    const float* s; bf16_t* d; int off;
    if (i < 131072) {
        int sg8 = i >> 15; off = i & 32767;
        s = sg8 == 0 ? s0 : sg8 == 1 ? s1 : sg8 == 2 ? s2 : s3;
        d = sg8 == 0 ? d0 : sg8 == 1 ? d1 : sg8 == 2 ? d2 : d3;
    } else if (i < 655360) { s = s4; d = d4; off = i - 131072; }
    else                   { s = s5; d = d5; off = i - 655360; }
    f32x4 v0 = ((const f32x4*)s)[off * 2];
    f32x4 v1 = ((const f32x4*)s)[off * 2 + 1];
    union { bf16_t b[8]; u32x4 u; } p;
    p.b[0] = (bf16_t)v0.x; p.b[1] = (bf16_t)v0.y;
    p.b[2] = (bf16_t)v0.z; p.b[3] = (bf16_t)v0.w;
    p.b[4] = (bf16_t)v1.x; p.b[5] = (bf16_t)v1.y;
    p.b[6] = (bf16_t)v1.z; p.b[7] = (bf16_t)v1.w;
    ((u32x4*)d)[off] = p.u;
}

// ---------------- RMSNorm (ln1): wave-per-row, f32x4 loads, grid 2048 ----------------
__global__ __launch_bounds__(256) void rmsnorm_kernel(const float* __restrict__ x,
                                                      const float* __restrict__ w,
                                                      bf16_t* __restrict__ out) {
    const int t = threadIdx.x, lane = t & 63, wave = t >> 6;
    const int row = blockIdx.x * 4 + wave;
    const float* xr = x + (size_t)row * 512 + lane * 8;
    f32x4 v0 = *(const f32x4*)(xr);
    f32x4 v1 = *(const f32x4*)(xr + 4);
    float ss = dot4(v0, v0) + dot4(v1, v1);
#pragma unroll
    for (int o = 32; o > 0; o >>= 1) ss += __shfl_xor(ss, o);
    float sc = rsqrtf(ss * (1.0f / 512.0f) + 1e-5f);
    f32x4 w0 = *(const f32x4*)(w + lane * 8);
    f32x4 w1 = *(const f32x4*)(w + lane * 8 + 4);
    union { bf16_t b[8]; u32x4 u; } p;
    p.b[0] = (bf16_t)(v0.x * sc * w0.x); p.b[1] = (bf16_t)(v0.y * sc * w0.y);
    p.b[2] = (bf16_t)(v0.z * sc * w0.z); p.b[3] = (bf16_t)(v0.w * sc * w0.w);
    p.b[4] = (bf16_t)(v1.x * sc * w1.x); p.b[5] = (bf16_t)(v1.y * sc * w1.y);
    p.b[6] = (bf16_t)(v1.z * sc * w1.z); p.b[7] = (bf16_t)(v1.w * sc * w1.w);
    *(u32x4*)(out + (size_t)row * 512 + lane * 8) = p.u;
}

// fast GELU (tanh-form via v_exp_f32): |err| <= ~3e-4 vs erf-GELU, << bf16 rounding.
__device__ inline float gelu_fast(float x) {
    float u = -1.5957691216f * x * fmaf(0.044715f * x, x, 1.0f);
    return x / (1.0f + __expf(u));
}

// ---------------- LDS XOR-swizzle GEMM compute (T2 both-sides, R12-verified) ----------
#define GEMM_COMPUTE(LA, LB)                                                          \
    _Pragma("unroll")                                                                 \
    for (int kk = 0; kk < 2; ++kk) {                                                  \
        bf16x8 af[4], bfr[4];                                                         \
        _Pragma("unroll")                                                             \
        for (int mi = 0; mi < 4; mi++)                                                \
            af[mi] = *(const bf16x8*)((LA) + (wr + mi * 16 + lrow) * 64               \
                                      + (((kk * 4 + sg) ^ lr3) * 8));                 \
        _Pragma("unroll")                                                             \
        for (int ni = 0; ni < 4; ni++)                                                \
            bfr[ni] = *(const bf16x8*)((LB) + (wc + ni * 16 + lrow) * 64              \
                                       + (((kk * 4 + sg) ^ lr3) * 8));                \
        _Pragma("unroll")                                                             \
        for (int mi = 0; mi < 4; mi++) {                                              \
            _Pragma("unroll")                                                         \
            for (int ni = 0; ni < 4; ni++) {                                          \
                acc[mi][ni] = __builtin_amdgcn_mfma_f32_16x16x32_bf16(                \
                    af[mi], bfr[ni], acc[mi][ni], 0, 0, 0);                           \
            }                                                                         \
        }                                                                             \
    }

// ---------------- dense bf16 MFMA GEMM 128x128 (R15 config) ----------------
// EPI: 1 = f32 out = acc + aux[idx]; 4 = bf16 out = acc. ncol in 128-col units.
template <int EPI>
__global__ __launch_bounds__(256) void gemm_kernel(const bf16_t* __restrict__ A,
                                                   const bf16_t* __restrict__ B,
                                                   void* __restrict__ C,
                                                   const float* __restrict__ aux,
                                                   int N, int K, int ncol) {
    const int id = xcd_swz(blockIdx.x, gridDim.x);
    const int row0 = (id / ncol) * 128;
    const int col0 = (id % ncol) * 128;
    __shared__ __align__(16) bf16_t lds_a[128 * 64];
    __shared__ __align__(16) bf16_t lds_b[128 * 64];
    const int t = threadIdx.x;
    const bf16_t* Ap = A + (size_t)row0 * K;
    const bf16_t* Bp = B + (size_t)col0 * K;
    const int lane = t & 63, wave = t >> 6;
    const int wr = (wave >> 1) * 64, wc = (wave & 1) * 64;
    const int lrow = lane & 15;
    const int sg = lane >> 4, lr3 = lane & 7;
    const int srow = lane >> 3;
    const int scolx = ((lane & 7) ^ (lane >> 3)) * 8;

    f32x4 acc[4][4];
    f32x4 zero = {0.f, 0.f, 0.f, 0.f};
#pragma unroll
    for (int i = 0; i < 4; i++)
#pragma unroll
        for (int j = 0; j < 4; j++) acc[i][j] = zero;

    for (int k0 = 0; k0 < K; k0 += 64) {
        __syncthreads();
#pragma unroll
        for (int c = 0; c < 4; ++c) {
            const int rbase = wave * 32 + c * 8;
            gl16(Ap + (size_t)(rbase + srow) * K + k0 + scolx, lds_a + rbase * 64);
            gl16(Bp + (size_t)(rbase + srow) * K + k0 + scolx, lds_b + rbase * 64);
        }
        __syncthreads();
        GEMM_COMPUTE(lds_a, lds_b)
    }

#pragma unroll
    for (int mi = 0; mi < 4; mi++) {
        int rbase = row0 + wr + mi * 16 + (lane >> 4) * 4;
#pragma unroll
        for (int ni = 0; ni < 4; ni++) {
            int col = col0 + wc + ni * 16 + (lane & 15);
#pragma unroll
            for (int r = 0; r < 4; r++) {
                float v = acc[mi][ni][r];
                size_t idx = (size_t)(rbase + r) * N + col;
                if (EPI == 1) ((float*)C)[idx] = v + aux[idx];
                else          ((bf16_t*)C)[idx] = (bf16_t)v;
            }
        }
    }
}

// ---------------- fused MoE fc: 128x64 tiles (R15 config), grid 4192 ----------------
__global__ __launch_bounds__(256) void moe_fc_kernel(
    const bf16_t* __restrict__ A, const bf16_t* __restrict__ B, bf16_t* __restrict__ H,
    const int* __restrict__ list, const int* __restrict__ cnt, const int* __restrict__ seg) {
    const int id = xcd_swz(blockIdx.x, gridDim.x);
    const int row0g = (id >> 5) * 128;        // ncol = 32
    const int col0 = (id & 31) * 64;
    int e = 0;
    if (row0g >= seg[1]) e = 1;
    if (row0g >= seg[2]) e = 2;
    if (row0g >= seg[3]) e = 3;
    const int ce = cnt[e];
    const int rl0 = row0g - seg[e];
    if (rl0 >= ce) return;   // gap: uniform exit before any barrier

    __shared__ __align__(16) bf16_t lds_a[128 * 64];   // 16 KB
    __shared__ __align__(16) bf16_t lds_b[64 * 64];    //  8 KB
    const int t = threadIdx.x;
    const bf16_t* Bp = B + ((size_t)e * 2048 + col0) * 512;
    const int* le = list + e * 8192;
    const int lane = t & 63, wave = t >> 6;
    const int wr = (wave >> 1) * 64, wc = (wave & 1) * 32;
    const int lrow = lane & 15;
    const int sg = lane >> 4, lr3 = lane & 7;
    const int srow = lane >> 3;
    const int scolx = ((lane & 7) ^ (lane >> 3)) * 8;

    const bf16_t* Asrc[4];
#pragma unroll
    for (int c = 0; c < 4; ++c) {
        int r = rl0 + wave * 32 + c * 8 + srow;
        r = (r < ce) ? r : (ce - 1);
        Asrc[c] = A + (size_t)le[r] * 512 + scolx;
    }

    f32x4 acc[4][2];
    f32x4 zero = {0.f, 0.f, 0.f, 0.f};
#pragma unroll
    for (int i = 0; i < 4; i++)
#pragma unroll
        for (int j = 0; j < 2; j++) acc[i][j] = zero;

    for (int k0 = 0; k0 < 512; k0 += 64) {
        __syncthreads();
#pragma unroll
        for (int c = 0; c < 4; ++c) {
            const int rbase = wave * 32 + c * 8;
            gl16(Asrc[c] + k0, lds_a + rbase * 64);
        }
        {
            const int rbase = wave * 16;
            gl16(Bp + (size_t)(rbase + srow) * 512 + k0 + scolx, lds_b + rbase * 64);
            gl16(Bp + (size_t)(rbase + 8 + srow) * 512 + k0 + scolx, lds_b + (rbase + 8) * 64);
        }
        __syncthreads();
#pragma unroll
        for (int kk = 0; kk < 2; ++kk) {
            bf16x8 af[4], bfr[2];
#pragma unroll
            for (int mi = 0; mi < 4; mi++)
                af[mi] = *(const bf16x8*)(lds_a + (wr + mi * 16 + lrow) * 64
                                          + (((kk * 4 + sg) ^ lr3) * 8));
#pragma unroll
            for (int ni = 0; ni < 2; ni++)
                bfr[ni] = *(const bf16x8*)(lds_b + (wc + ni * 16 + lrow) * 64
                                           + (((kk * 4 + sg) ^ lr3) * 8));
#pragma unroll
            for (int mi = 0; mi < 4; mi++) {
#pragma unroll
                for (int ni = 0; ni < 2; ni++) {
                    acc[mi][ni] = __builtin_amdgcn_mfma_f32_16x16x32_bf16(
                        af[mi], bfr[ni], acc[mi][ni], 0, 0, 0);
                }
            }
        }
    }

#pragma unroll
    for (int mi = 0; mi < 4; mi++) {
        int rbase = row0g + wr + mi * 16 + (lane >> 4) * 4;
#pragma unroll
        for (int ni = 0; ni < 2; ni++) {
            int col = col0 + wc + ni * 16 + (lane & 15);
#pragma unroll
            for (int r = 0; r < 4; r++) {
                // rows beyond cnt within block are dup garbage; proj discards them
                H[(size_t)(rbase + r) * 2048 + col] = (bf16_t)gelu_fast(acc[mi][ni][r]);
            }
        }
    }
}

// ---------------- fused MoE proj: 64x64 tiles (R15-proven), grid 2096 ----------------
__global__ __launch_bounds__(256) void moe_pj_kernel(
    const bf16_t* __restrict__ H, const bf16_t* __restrict__ B, float* __restrict__ xout,
    const float* __restrict__ rw, const int* __restrict__ list,
    const int* __restrict__ cnt, const int* __restrict__ seg) {
    const int id = xcd_swz(blockIdx.x, gridDim.x);
    const int row0g = (id >> 3) * 64;
    const int col0 = (id & 7) * 64;
    int e = 0;
    if (row0g >= seg[1]) e = 1;
    if (row0g >= seg[2]) e = 2;
    if (row0g >= seg[3]) e = 3;
    const int ce = cnt[e];
    const int se = seg[e];
    const int rl0 = row0g - se;
    if (rl0 >= ce) return;

    __shared__ __align__(16) bf16_t lds_a[64 * 64];    // 8 KB
    __shared__ __align__(16) bf16_t lds_b[64 * 64];    // 8 KB
    const int t = threadIdx.x;
    const bf16_t* Ap = H + (size_t)row0g * 2048;
    const bf16_t* Bp = B + ((size_t)e * 512 + col0) * 2048;
    const int* le = list + e * 8192;
    const int lane = t & 63, wave = t >> 6;
    const int wr = (wave >> 1) * 32, wc = (wave & 1) * 32;
    const int lrow = lane & 15;
    const int sg = lane >> 4, lr3 = lane & 7;
    const int srow = lane >> 3;
    const int scolx = ((lane & 7) ^ (lane >> 3)) * 8;

    f32x4 acc[2][2];
    f32x4 zero = {0.f, 0.f, 0.f, 0.f};
#pragma unroll
    for (int i = 0; i < 2; i++)
#pragma unroll
        for (int j = 0; j < 2; j++) acc[i][j] = zero;

    for (int k0 = 0; k0 < 2048; k0 += 64) {
        __syncthreads();
#pragma unroll
        for (int c = 0; c < 2; ++c) {
            const int rbase = wave * 16 + c * 8;
            gl16(Ap + (size_t)(rbase + srow) * 2048 + k0 + scolx, lds_a + rbase * 64);
            gl16(Bp + (size_t)(rbase + srow) * 2048 + k0 + scolx, lds_b + rbase * 64);
        }
        __syncthreads();
#pragma unroll
        for (int kk = 0; kk < 2; ++kk) {
            bf16x8 af[2], bfr[2];
#pragma unroll
            for (int mi = 0; mi < 2; mi++)
                af[mi] = *(const bf16x8*)(lds_a + (wr + mi * 16 + lrow) * 64
                                          + (((kk * 4 + sg) ^ lr3) * 8));
#pragma unroll
            for (int ni = 0; ni < 2; ni++)
                bfr[ni] = *(const bf16x8*)(lds_b + (wc + ni * 16 + lrow) * 64
                                           + (((kk * 4 + sg) ^ lr3) * 8));
#pragma unroll
            for (int mi = 0; mi < 2; mi++) {
#pragma unroll
                for (int ni = 0; ni < 2; ni++) {
                    acc[mi][ni] = __builtin_amdgcn_mfma_f32_16x16x32_bf16(
                        af[mi], bfr[ni], acc[mi][ni], 0, 0, 0);
                }
            }
        }
    }

#pragma unroll
    for (int mi = 0; mi < 2; mi++) {
        int rbase = row0g + wr + mi * 16 + (lane >> 4) * 4;
#pragma unroll
        for (int ni = 0; ni < 2; ni++) {
            int col = col0 + wc + ni * 16 + (lane & 15);
#pragma unroll
            for (int r = 0; r < 4; r++) {
                int rloc = rbase + r - se;
                if (rloc < ce) {
                    int tok = le[rloc];
                    atomicAdd(xout + (size_t)tok * 512 + col,
                              rw[(size_t)tok * 4 + e] * acc[mi][ni][r]);
                }
            }
        }
    }
}

// ---------------- MFMA causal flash attention (load-ahead + T5 setprio) ----------------
__global__ __launch_bounds__(256) void attn_kernel(const bf16_t* __restrict__ QKV,
                                                   bf16_t* __restrict__ O) {
    __shared__ __align__(16) bf16_t klds[2 * 64 * 32];
    __shared__ __align__(16) bf16_t vlds[4 * 2 * 16 * 32];

    const int bx = blockIdx.x;
    const int qb = 15 - (bx >> 6);
    const int bh = bx & 63;
    const int b = bh >> 3, h = bh & 7;
    const int t = threadIdx.x;
    const int lane = t & 63, wave = t >> 6;
    const int g = lane >> 4, q15 = lane & 15;
    const int qbase = qb * 64 + wave * 16;
    const int qabs = qbase + q15;

    const bf16_t* Qb = QKV + (size_t)b * 1024 * 1536 + h * 64;
    const bf16_t* Kb = Qb + 512;
    const bf16_t* Vb = Qb + 1024;

    const bf16_t* qp = Qb + (size_t)qabs * 1536 + g * 8;
    bf16x8 qf0 = *(const bf16x8*)(qp);
    bf16x8 qf1 = *(const bf16x8*)(qp + 32);

    f32x4 acc[4];
    f32x4 zero = {0.f, 0.f, 0.f, 0.f};
#pragma unroll
    for (int i = 0; i < 4; i++) acc[i] = zero;
    float m = -1e30f, denom = 0.f;

    const int kr1 = t >> 3, kc1 = t & 7;
    const int vr = t & 63, vc1 = t >> 6, vc2 = vc1 + 4;
    const int perm = ((q15 >> 2) * 8) + (q15 & 3);

    const int nkt = qb + 1;
    u32x4 ka  = *(const u32x4*)(Kb + (size_t)(kr1) * 1536 + kc1 * 8);
    u32x4 kb2 = *(const u32x4*)(Kb + (size_t)(kr1 + 32) * 1536 + kc1 * 8);
    u32x4 va  = *(const u32x4*)(Vb + (size_t)(vr) * 1536 + vc1 * 8);
    u32x4 vb2 = *(const u32x4*)(Vb + (size_t)(vr) * 1536 + vc2 * 8);

    for (int kt = 0; kt < nkt; ++kt) {
        __syncthreads();
        *(u32x4*)(klds + (kc1 >> 2) * 2048 + kr1 * 32 + (kc1 & 3) * 8) = ka;
        *(u32x4*)(klds + (kc1 >> 2) * 2048 + (kr1 + 32) * 32 + (kc1 & 3) * 8) = kb2;
        {
            union { u32x4 u; bf16_t e[8]; } tv;
            const int kh = vr >> 5, k32 = vr & 31;
            tv.u = va;
#pragma unroll
            for (int j = 0; j < 8; ++j) {
                int d = vc1 * 8 + j;
                vlds[(((d >> 4) * 2 + kh) * 16 + (d & 15)) * 32 + k32] = tv.e[j];
            }
            tv.u = vb2;
#pragma unroll
            for (int j = 0; j < 8; ++j) {
                int d = vc2 * 8 + j;
                vlds[(((d >> 4) * 2 + kh) * 16 + (d & 15)) * 32 + k32] = tv.e[j];
            }
        }
        __syncthreads();

        if (kt + 1 < nkt) {
            const size_t krow = (size_t)((kt + 1) * 64);
            ka  = *(const u32x4*)(Kb + (krow + kr1) * 1536 + kc1 * 8);
            kb2 = *(const u32x4*)(Kb + (krow + kr1 + 32) * 1536 + kc1 * 8);
            va  = *(const u32x4*)(Vb + (krow + vr) * 1536 + vc1 * 8);
            vb2 = *(const u32x4*)(Vb + (krow + vr) * 1536 + vc2 * 8);
        }

        for (int s32 = 0; s32 < 2; ++s32) {
            const int KB = kt * 64 + s32 * 32;
            if (KB > qbase + 15) break;
            const int r0 = s32 * 32 + perm;
            bf16x8 k00 = *(const bf16x8*)(klds + r0 * 32 + g * 8);
            bf16x8 k01 = *(const bf16x8*)(klds + 2048 + r0 * 32 + g * 8);
            bf16x8 k10 = *(const bf16x8*)(klds + (r0 + 4) * 32 + g * 8);
            bf16x8 k11 = *(const bf16x8*)(klds + 2048 + (r0 + 4) * 32 + g * 8);
            f32x4 s0 = zero, s1 = zero;
            __builtin_amdgcn_s_setprio(1);
            s0 = __builtin_amdgcn_mfma_f32_16x16x32_bf16(k00, qf0, s0, 0, 0, 0);
            s0 = __builtin_amdgcn_mfma_f32_16x16x32_bf16(k01, qf1, s0, 0, 0, 0);
            s1 = __builtin_amdgcn_mfma_f32_16x16x32_bf16(k10, qf0, s1, 0, 0, 0);
            s1 = __builtin_amdgcn_mfma_f32_16x16x32_bf16(k11, qf1, s1, 0, 0, 0);
            __builtin_amdgcn_s_setprio(0);

            const int kbg = KB + 8 * g;
            float sv[8];
#pragma unroll
            for (int r = 0; r < 4; ++r) {
                sv[r]     = (kbg + r     <= qabs) ? s0[r] * 0.125f : -1e30f;
                sv[4 + r] = (kbg + 4 + r <= qabs) ? s1[r] * 0.125f : -1e30f;
            }
            float tm = sv[0];
#pragma unroll
            for (int j = 1; j < 8; ++j) tm = fmaxf(tm, sv[j]);
            tm = fmaxf(tm, __shfl_xor(tm, 16));
            tm = fmaxf(tm, __shfl_xor(tm, 32));
            const float mn = fmaxf(m, tm);
            const float co = __expf(m - mn);
            float p[8];
            float ts = 0.f;
#pragma unroll
            for (int j = 0; j < 8; ++j) { p[j] = __expf(sv[j] - mn); ts += p[j]; }
            ts += __shfl_xor(ts, 16);
            ts += __shfl_xor(ts, 32);
            denom = denom * co + ts;
            m = mn;
            union { bf16_t e[8]; bf16x8 v; } pp;
#pragma unroll
            for (int j = 0; j < 8; ++j) pp.e[j] = (bf16_t)p[j];

            __builtin_amdgcn_s_setprio(1);
#pragma unroll
            for (int db = 0; db < 4; ++db) {
                acc[db] *= co;
                bf16x8 vf = *(const bf16x8*)(vlds + ((db * 2 + s32) * 16 + q15) * 32 + g * 8);
                acc[db] = __builtin_amdgcn_mfma_f32_16x16x32_bf16(vf, pp.v, acc[db], 0, 0, 0);
            }
            __builtin_amdgcn_s_setprio(0);
        }
    }

    const float inv = 1.0f / denom;
    bf16_t* op = O + (size_t)b * 1024 * 512 + h * 64 + (size_t)qabs * 512;
#pragma unroll
    for (int db = 0; db < 4; ++db) {
        union { bf16_t e[4]; u32x2 u; } w;
#pragma unroll
        for (int r = 0; r < 4; ++r) w.e[r] = (bf16_t)(acc[db][r] * inv);
        *(u32x2*)(op + db * 16 + g * 4) = w.u;
    }
}

// 128-aligned exclusive prefix of cnt -> seg (padded compact H segments)
__global__ void seg_kernel(const int* __restrict__ cnt, int* __restrict__ seg) {
    if (threadIdx.x == 0) {
        int b = 0;
#pragma unroll
        for (int e = 0; e < 4; ++e) { seg[e] = b; b += (cnt[e] + 127) & ~127; }
    }
}

// ---------------- router: fused rmsnorm2 + gate + top2 + compaction ----------------
__global__ __launch_bounds__(256) void router_kernel(
    const float* __restrict__ xr, const float* __restrict__ w,
    const float* __restrict__ gw, bf16_t* __restrict__ hb,
    float* __restrict__ rout, int* __restrict__ list, int* __restrict__ cnt) {
    __shared__ int lcnt[4], gb[4];
    __shared__ int ent_tok[64], ent_e[64], ent_r[64];
    const int t = threadIdx.x, lane = t & 63, wave = t >> 6;
    if (t < 4) lcnt[t] = 0;
    __syncthreads();

    const f32x4 w0  = *(const f32x4*)(w + lane * 8);
    const f32x4 w1  = *(const f32x4*)(w + lane * 8 + 4);
    const f32x4 g00 = *(const f32x4*)(gw + lane * 8);
    const f32x4 g01 = *(const f32x4*)(gw + lane * 8 + 4);
    const f32x4 g10 = *(const f32x4*)(gw + 512 + lane * 8);
    const f32x4 g11 = *(const f32x4*)(gw + 512 + lane * 8 + 4);
    const f32x4 g20 = *(const f32x4*)(gw + 1024 + lane * 8);
    const f32x4 g21 = *(const f32x4*)(gw + 1024 + lane * 8 + 4);
    const f32x4 g30 = *(const f32x4*)(gw + 1536 + lane * 8);
    const f32x4 g31 = *(const f32x4*)(gw + 1536 + lane * 8 + 4);

    for (int it = 0; it < 8; ++it) {
        const int tok = blockIdx.x * 32 + wave * 8 + it;
        const float* row = xr + (size_t)tok * 512 + lane * 8;
        f32x4 v0 = *(const f32x4*)(row);
        f32x4 v1 = *(const f32x4*)(row + 4);
        float ss = dot4(v0, v0) + dot4(v1, v1);
        f32x4 xw0, xw1;
        xw0.x = v0.x * w0.x; xw0.y = v0.y * w0.y; xw0.z = v0.z * w0.z; xw0.w = v0.w * w0.w;
        xw1.x = v1.x * w1.x; xw1.y = v1.y * w1.y; xw1.z = v1.z * w1.z; xw1.w = v1.w * w1.w;
        float d0 = dot4(xw0, g00) + dot4(xw1, g01);
        float d1 = dot4(xw0, g10) + dot4(xw1, g11);
        float d2 = dot4(xw0, g20) + dot4(xw1, g21);
        float d3 = dot4(xw0, g30) + dot4(xw1, g31);
#pragma unroll
        for (int o = 32; o > 0; o >>= 1) {
            ss += __shfl_xor(ss, o);
            d0 += __shfl_xor(d0, o);
            d1 += __shfl_xor(d1, o);
            d2 += __shfl_xor(d2, o);
            d3 += __shfl_xor(d3, o);
        }
        const float sc = rsqrtf(ss * (1.0f / 512.0f) + 1e-5f);
        union { bf16_t b[8]; u32x4 u; } hw;
        hw.b[0] = (bf16_t)(xw0.x * sc); hw.b[1] = (bf16_t)(xw0.y * sc);
        hw.b[2] = (bf16_t)(xw0.z * sc); hw.b[3] = (bf16_t)(xw0.w * sc);
        hw.b[4] = (bf16_t)(xw1.x * sc); hw.b[5] = (bf16_t)(xw1.y * sc);
        hw.b[6] = (bf16_t)(xw1.z * sc); hw.b[7] = (bf16_t)(xw1.w * sc);
        *(u32x4*)(hb + (size_t)tok * 512 + lane * 8) = hw.u;

        const float l0 = d0 * sc, l1 = d1 * sc, l2 = d2 * sc, l3 = d3 * sc;
        float mx = fmaxf(fmaxf(l0, l1), fmaxf(l2, l3));
        float p[4];
        p[0] = expf(l0 - mx); p[1] = expf(l1 - mx);
        p[2] = expf(l2 - mx); p[3] = expf(l3 - mx);
        float s = (p[0] + p[1]) + (p[2] + p[3]);
        float is = 1.0f / s;
        p[0] *= is; p[1] *= is; p[2] *= is; p[3] *= is;
        int i0 = 0; float b0 = p[0];
#pragma unroll
        for (int e = 1; e < 4; e++) if (p[e] > b0) { b0 = p[e]; i0 = e; }
        int i1 = -1; float b1 = -1.f;
#pragma unroll
        for (int e = 0; e < 4; e++) {
            if (e == i0) continue;
            if (p[e] > b1) { b1 = p[e]; i1 = e; }
        }
        if (lane == 0) {
            float inv2 = 1.0f / fmaxf(b0 + b1, 1e-6f);
            float o[4] = {0.f, 0.f, 0.f, 0.f};
            o[i0] = b0 * inv2;
            o[i1] = b1 * inv2;
            f32x4 ov; ov.x = o[0]; ov.y = o[1]; ov.z = o[2]; ov.w = o[3];
            *(f32x4*)(rout + (size_t)tok * 4) = ov;
            int r0 = atomicAdd(&lcnt[i0], 1);
            int r1 = atomicAdd(&lcnt[i1], 1);
            int ei = (wave * 8 + it) * 2;
            ent_tok[ei] = tok;     ent_e[ei] = i0;     ent_r[ei] = r0;
            ent_tok[ei + 1] = tok; ent_e[ei + 1] = i1; ent_r[ei + 1] = r1;
        }
    }
    __syncthreads();
    if (t < 4) gb[t] = atomicAdd(&cnt[t], lcnt[t]);
    __syncthreads();
    if (t < 64) {
        int e = ent_e[t];
        list[e * 8192 + gb[e] + ent_r[t]] = ent_tok[t];
    }
}

extern "C" void kernel_launch(void* const* d_in, const int* in_sizes, int n_in,
                              void* d_out, int out_size, void* d_ws, size_t ws_size,
                              hipStream_t stream) {
    (void)in_sizes; (void)n_in; (void)out_size; (void)ws_size;
    const float* x   = (const float*)d_in[0];
    const float* ln1 = (const float*)d_in[1];
    const float* ln2 = (const float*)d_in[2];
    const float* wq  = (const float*)d_in[3];
    const float* wk  = (const float*)d_in[4];
    const float* wv  = (const float*)d_in[5];
    const float* wo  = (const float*)d_in[6];
    const float* gw  = (const float*)d_in[7];
    const float* wfc = (const float*)d_in[8];
    const float* wpj = (const float*)d_in[9];

    char* ws = (char*)d_ws;
    bf16_t* hb    = (bf16_t*)(ws);
    bf16_t* qkvb  = (bf16_t*)(ws + 8 * WS_MB);
    bf16_t* attb  = (bf16_t*)(ws + 32 * WS_MB);
    bf16_t* Hb    = (bf16_t*)(ws + 8 * WS_MB);   // padded compact H, overlaps qkv/att
    bf16_t* wqkvb = (bf16_t*)(ws + 74 * WS_MB);
    bf16_t* wob   = (bf16_t*)(ws + 74 * WS_MB + 1536 * 1024);
    bf16_t* wfcb  = (bf16_t*)(ws + 76 * WS_MB);
    bf16_t* wpjb  = (bf16_t*)(ws + 84 * WS_MB);
    int*    list  = (int*)(ws + 92 * WS_MB);      // [4][8192]
    int*    cnt   = (int*)(ws + 92 * WS_MB + 192 * 1024);
    int*    seg   = cnt + 8;

    float* xout   = (float*)d_out;
    float* router = xout + (size_t)8192 * 512;

    cvt_all_kernel<<<4608, 256, 0, stream>>>(wq, wk, wv, wo, wfc, wpj,
                                             wqkvb, wqkvb + 512 * 512, wqkvb + 1024 * 512,
                                             wob, wfcb, wpjb, cnt);

    rmsnorm_kernel<<<2048, 256, 0, stream>>>(x, ln1, hb);
    gemm_kernel<4><<<768, 256, 0, stream>>>(hb, wqkvb, (void*)qkvb, nullptr, 1536, 512, 12);

    attn_kernel<<<1024, 256, 0, stream>>>(qkvb, attb);

    gemm_kernel<1><<<256, 256, 0, stream>>>(attb, wob, (void*)xout, x, 512, 512, 4);

    router_kernel<<<256, 256, 0, stream>>>(xout, ln2, gw, hb, router, list, cnt);
    seg_kernel<<<1, 64, 0, stream>>>(cnt, seg);

    // fused MoE: fc 128x64 tiles (4192 blocks) + pj 64x64 tiles (2096 blocks)
    moe_fc_kernel<<<32 * 131, 256, 0, stream>>>(hb, wfcb, Hb, list, cnt, seg);
    moe_pj_kernel<<<8 * 262, 256, 0, stream>>>(Hb, wpjb, xout, router, list, cnt, seg);
}